// Round 8
// baseline (890.005 us; speedup 1.0000x reference)
//
#include <hip/hip_runtime.h>
#include <hip/hip_cooperative_groups.h>

// patient_GCN: 2x GCNConv(128->128) + mean-pool + head.
// R8: ONE cooperative mega-kernel, grid.sync() between phases.
// 512 blocks x 256 thr, __launch_bounds__(256,2) -> 2 blocks/CU co-resident.
// Phases: deg(+wprep+gbounds+axhead) | local-scan | global-scan | offsets |
//         fill||gemm1 | agg1 | gemm2 | agg2 | pool | head.

namespace cg = cooperative_groups;

#define NBLK 512

typedef __attribute__((ext_vector_type(8))) short bf16x8;
typedef __attribute__((ext_vector_type(4))) float f32x4;
typedef __attribute__((ext_vector_type(2))) float f32x2;

static __device__ __forceinline__ unsigned short f2bf(float f) {
  unsigned u = __float_as_uint(f);
  return (unsigned short)((u + 0x7fffu + ((u >> 16) & 1u)) >> 16);
}
static __device__ __forceinline__ unsigned pack2(float a, float b) {
  return (unsigned)f2bf(a) | ((unsigned)f2bf(b) << 16);
}
static __device__ __forceinline__ unsigned char f2fp8(float v) {
  return (unsigned char)(__builtin_amdgcn_cvt_pk_fp8_f32(v, 0.f, 0, false) & 0xff);
}
static __device__ __forceinline__ void add16(float* a, uint4 h) {
  f32x2 t;
  t = __builtin_amdgcn_cvt_pk_f32_fp8(h.x, false); a[0] += t[0]; a[1] += t[1];
  t = __builtin_amdgcn_cvt_pk_f32_fp8(h.x, true);  a[2] += t[0]; a[3] += t[1];
  t = __builtin_amdgcn_cvt_pk_f32_fp8(h.y, false); a[4] += t[0]; a[5] += t[1];
  t = __builtin_amdgcn_cvt_pk_f32_fp8(h.y, true);  a[6] += t[0]; a[7] += t[1];
  t = __builtin_amdgcn_cvt_pk_f32_fp8(h.z, false); a[8] += t[0]; a[9] += t[1];
  t = __builtin_amdgcn_cvt_pk_f32_fp8(h.z, true);  a[10] += t[0]; a[11] += t[1];
  t = __builtin_amdgcn_cvt_pk_f32_fp8(h.w, false); a[12] += t[0]; a[13] += t[1];
  t = __builtin_amdgcn_cvt_pk_f32_fp8(h.w, true);  a[14] += t[0]; a[15] += t[1];
}

struct Params {
  const float* x; const int* srcv; const int* dstv; const int* bat;
  const float* axd;
  const float* W1; const float* b1; const float* W2; const float* b2;
  const float* l1W; const float* l1b; const float* axW; const float* axb;
  const float* l2W; const float* l2b;
  float* out;
  unsigned char* h8; unsigned short* habuf;
  unsigned short* wt1; unsigned short* wt2;
  int* csr; int* offs; int* cursor8; int* cnt8;
  float* ps; float* dinv;
  int* partial; int* ppre; int* gstart; float* zax;
  int n, E, G;
};

// ---- GEMM phase: H8[tile rows,128](fp8) = dinv[m]*(X@W); W^T pre-staged once ----
template <bool FP32IN>
static __device__ void gemm_phase(const void* Xv, const unsigned short* wtglob,
                                  const float* dinv, unsigned char* H8, int M,
                                  int bg, int gstride,
                                  unsigned short* sW, unsigned short* sX, int tid) {
  const uint4* WT4 = (const uint4*)wtglob;
#pragma unroll
  for (int r = 0; r < 8; r++) {
    int idx = tid + r * 256;
    int nn = idx >> 4, c8 = idx & 15;
    *(uint4*)(sW + nn * 136 + c8 * 8) = WT4[idx];
  }
  int ntiles = (M + 63) >> 6;
  int lane = tid & 63, wv = tid >> 6;
  int ln15 = lane & 15, q = lane >> 4;
  for (int tile = bg; tile < ntiles; tile += gstride) {
    int m0 = tile * 64;
    if (FP32IN) {
      const float4* X4 = (const float4*)Xv;
#pragma unroll
      for (int r = 0; r < 8; r++) {
        int idx = tid + r * 256;
        int rr = idx >> 5, c4 = idx & 31;
        int m = m0 + rr;
        float4 v = make_float4(0.f, 0.f, 0.f, 0.f);
        if (m < M) v = X4[(size_t)m * 32 + c4];
        unsigned short* p = sX + rr * 136 + c4 * 4;
        *(ushort2*)(p) = make_ushort2(f2bf(v.x), f2bf(v.y));
        *(ushort2*)(p + 2) = make_ushort2(f2bf(v.z), f2bf(v.w));
      }
    } else {
      const uint4* X4 = (const uint4*)Xv;
#pragma unroll
      for (int r = 0; r < 4; r++) {
        int idx = tid + r * 256;
        int rr = idx >> 4, c8 = idx & 15;
        int m = m0 + rr;
        uint4 v = make_uint4(0u, 0u, 0u, 0u);
        if (m < M) v = X4[(size_t)m * 16 + c8];
        *(uint4*)(sX + rr * 136 + c8 * 8) = v;
      }
    }
    __syncthreads();
    bf16x8 afrag[4];
#pragma unroll
    for (int c = 0; c < 4; c++)
      afrag[c] = *(const bf16x8*)(sX + (wv * 16 + ln15) * 136 + c * 32 + q * 8);
    int r0 = m0 + wv * 16 + q * 4;
    float dv[4];
#pragma unroll
    for (int rr = 0; rr < 4; rr++) dv[rr] = (r0 + rr < M) ? dinv[r0 + rr] : 0.f;
#pragma unroll
    for (int j = 0; j < 8; j++) {
      f32x4 acc = {0.f, 0.f, 0.f, 0.f};
#pragma unroll
      for (int c = 0; c < 4; c++) {
        bf16x8 bfrag = *(const bf16x8*)(sW + (j * 16 + ln15) * 136 + c * 32 + q * 8);
        acc = __builtin_amdgcn_mfma_f32_16x16x32_bf16(afrag[c], bfrag, acc, 0, 0, 0);
      }
      int col = j * 16 + ln15;
#pragma unroll
      for (int rr = 0; rr < 4; rr++) {
        int m = r0 + rr;
        if (m < M) H8[(size_t)m * 128 + col] = f2fp8(dv[rr] * acc[rr]);
      }
    }
    __syncthreads();
  }
}

// ---- agg phase: out[i]=relu(b+dinv[i]*(Hs[i]+sum Hs[src])) over grid-stride ----
static __device__ void agg_phase(const uint4* Hs, const int* csr, const int* offs,
                                 const float* dinv, const float* bias, uint4* Ho,
                                 int n, int b, int tid) {
  int lane = tid & 63, wv = tid >> 6;
  int oct = lane >> 3, k = lane & 7;
  for (int i = b * 4 + wv; i < n; i += NBLK * 4) {
    int e0 = offs[i], e1 = offs[i + 1];
    int deg = e1 - e0;
    int adj = (lane < deg) ? csr[e0 + lane] : 0;
    float acc[16];
#pragma unroll
    for (int r = 0; r < 16; r++) acc[r] = 0.f;
    if (oct == 0) {
      uint4 h = Hs[(size_t)i * 8 + k];
      add16(acc, h);
    }
    int dcap = deg < 64 ? deg : 64;
    int j = 0;
#pragma unroll 2
    for (; j + 8 <= dcap; j += 8) {
      int s = __shfl(adj, j + oct);
      uint4 h = Hs[(size_t)s * 8 + k];
      add16(acc, h);
    }
    int rem = dcap - j;
    {
      int idx = j + oct;
      int s = __shfl(adj, idx < dcap ? idx : 0);
      if (oct < rem) {
        uint4 h = Hs[(size_t)s * 8 + k];
        add16(acc, h);
      }
    }
    for (int e = e0 + 64; e < e1; e += 8) {
      if (oct < e1 - e) {
        int s = csr[e + oct];
        uint4 h = Hs[(size_t)s * 8 + k];
        add16(acc, h);
      }
    }
#pragma unroll
    for (int r = 0; r < 16; r++) {
      acc[r] += __shfl_xor(acc[r], 8);
      acc[r] += __shfl_xor(acc[r], 16);
      acc[r] += __shfl_xor(acc[r], 32);
    }
    if (oct == 0) {
      float di = dinv[i];
      const float4* B4 = (const float4*)bias;
      float o[16];
#pragma unroll
      for (int m4 = 0; m4 < 4; m4++) {
        float4 bb = B4[k * 4 + m4];
        o[m4 * 4 + 0] = fmaxf(bb.x + di * acc[m4 * 4 + 0], 0.f);
        o[m4 * 4 + 1] = fmaxf(bb.y + di * acc[m4 * 4 + 1], 0.f);
        o[m4 * 4 + 2] = fmaxf(bb.z + di * acc[m4 * 4 + 2], 0.f);
        o[m4 * 4 + 3] = fmaxf(bb.w + di * acc[m4 * 4 + 3], 0.f);
      }
      uint4 r0, r1;
      r0.x = pack2(o[0], o[1]);   r0.y = pack2(o[2], o[3]);
      r0.z = pack2(o[4], o[5]);   r0.w = pack2(o[6], o[7]);
      r1.x = pack2(o[8], o[9]);   r1.y = pack2(o[10], o[11]);
      r1.z = pack2(o[12], o[13]); r1.w = pack2(o[14], o[15]);
      Ho[(size_t)i * 16 + 2 * k] = r0;
      Ho[(size_t)i * 16 + 2 * k + 1] = r1;
    }
  }
}

__global__ __launch_bounds__(256, 2) void megakernel(Params P) {
  cg::grid_group grid = cg::this_grid();
  __shared__ __align__(16) unsigned char smem[52224];
  unsigned short* sW = (unsigned short*)smem;            // 34816 B
  unsigned short* sX = (unsigned short*)(smem + 34816);  // 17408 B
  int* sTot = (int*)smem;                                 // 128 ints @0
  int* sPre = (int*)(smem + 512);                         // 128 ints
  int* sScan = (int*)(smem + 1024);                       // 512 ints
  float* hp = (float*)smem;                               // head p[128]
  float* hz = (float*)(smem + 512);                       // head z[192]

  int b = blockIdx.x, t = threadIdx.x;
  int n = P.n, E = P.E, G = P.G;
  int EPB = E / NBLK;  // 1250

  // ---------- P0: deg (privatized) + wprep + gbounds + ax-head ----------
  {
    int base = b * EPB, c = b & 7;
    for (int k = 0; k < EPB; k += 256) {
      int o = k + t;
      if (o < EPB) atomicAdd(&P.cnt8[c * n + P.dstv[base + o]], 1);
    }
    if (t < 64) {
      int idx = b * 64 + t;  // 32768 total
      int w = idx >> 14, r = (idx >> 7) & 127, k = idx & 127;
      if (w == 0) P.wt1[r * 128 + k] = f2bf(P.W1[k * 128 + r]);
      else        P.wt2[r * 128 + k] = f2bf(P.W2[k * 128 + r]);
    }
    if (b == 0) {
      for (int g0 = t; g0 <= G; g0 += 256) {
        if (g0 == G) P.gstart[g0] = n;
        else {
          int lo = 0, hi = n;
          while (lo < hi) {
            int mid = (lo + hi) >> 1;
            if (P.bat[mid] < g0) lo = mid + 1; else hi = mid;
          }
          P.gstart[g0] = lo;
        }
      }
    }
    if (b < G && t < 64) {
      float acc = P.axb[t];
      for (int k = 0; k < 64; k++) acc += P.axd[b * 64 + k] * P.axW[k * 64 + t];
      P.zax[b * 64 + t] = acc;
    }
  }
  grid.sync();

  // ---------- P1: per-block local scan of node totals ----------
  int CH = (n + NBLK - 1) / NBLK;  // 98
  int n0 = b * CH;
  int cnt = n - n0; if (cnt > CH) cnt = CH;
  {
    if (t < cnt) {
      int node = n0 + t, tot = 0;
#pragma unroll
      for (int c = 0; c < 8; c++) tot += P.cnt8[c * n + node];
      sTot[t] = tot;
    }
    __syncthreads();
    if (t == 0) {
      int run = 0;
      for (int j = 0; j < cnt; j++) { sPre[j] = run; run += sTot[j]; }
      P.partial[b] = run;
    }
  }
  grid.sync();

  // ---------- P2: block 0 scans 512 partials ----------
  if (b == 0) {
    int a0 = P.partial[2 * t], a1 = P.partial[2 * t + 1];
    sScan[t] = a0 + a1;
    __syncthreads();
    for (int o = 1; o < 256; o <<= 1) {
      int v = (t >= o) ? sScan[t - o] : 0;
      __syncthreads();
      sScan[t] += v;
      __syncthreads();
    }
    int incl = sScan[t];
    P.ppre[2 * t] = incl - a0 - a1;
    P.ppre[2 * t + 1] = incl - a1;
    if (t == 255) P.offs[n] = incl;
  }
  grid.sync();

  // ---------- P3: offsets + 8 segment cursors + dinv ----------
  if (t < cnt) {
    int node = n0 + t;
    int off = P.ppre[b] + sPre[t];
    P.offs[node] = off;
    int run = off;
#pragma unroll
    for (int c = 0; c < 8; c++) {
      P.cursor8[c * n + node] = run;
      run += P.cnt8[c * n + node];
    }
    P.dinv[node] = rsqrtf((float)(sTot[t] + 1));
  }
  grid.sync();

  // ---------- P4: fill (blocks 0-255) || gemm1 (blocks 256-511) ----------
  if (b < 256) {
    int base2 = b * 2 * EPB;  // 2500 edges/block
    int lim = 2 * EPB;
    for (int k = 0; k < lim; k += 256) {
      int o = k + t;
      if (o < lim) {
        int e = base2 + o;
        int cc = (2 * b + (o >= EPB ? 1 : 0)) & 7;  // same e->copy map as P0
        int p = atomicAdd(&P.cursor8[cc * n + P.dstv[e]], 1);
        P.csr[p] = P.srcv[e];
      }
    }
  } else {
    gemm_phase<true>(P.x, P.wt1, P.dinv, P.h8, n, b - 256, 256, sW, sX, t);
  }
  grid.sync();

  // ---------- P5: agg1 ----------
  agg_phase((const uint4*)P.h8, P.csr, P.offs, P.dinv, P.b1,
            (uint4*)P.habuf, n, b, t);
  grid.sync();

  // ---------- P6: gemm2 ----------
  gemm_phase<false>(P.habuf, P.wt2, P.dinv, P.h8, n, b, NBLK, sW, sX, t);
  grid.sync();

  // ---------- P7: agg2 ----------
  agg_phase((const uint4*)P.h8, P.csr, P.offs, P.dinv, P.b2,
            (uint4*)P.habuf, n, b, t);
  grid.sync();

  // ---------- P8: pool (segmented atomic sum, 128 rows per block) ----------
  {
    int vb = b;
    int r0v = vb * 128;
    if (r0v < n) {
      int ln = t & 63, sub = t >> 6;
      int rend = r0v + 128; if (rend > n) rend = n;
      const unsigned* H2 = (const unsigned*)P.habuf;
      float ax = 0.f, ay = 0.f;
      int curg = -1;
      for (int r = r0v + sub; r < rend; r += 4) {
        int g = P.bat[r];
        if (g != curg) {
          if (curg >= 0) {
            atomicAdd(&P.ps[curg * 128 + 2 * ln], ax);
            atomicAdd(&P.ps[curg * 128 + 2 * ln + 1], ay);
          }
          curg = g; ax = 0.f; ay = 0.f;
        }
        unsigned h = H2[(size_t)r * 64 + ln];
        ax += __uint_as_float(h << 16);
        ay += __uint_as_float(h & 0xffff0000u);
      }
      if (curg >= 0) {
        atomicAdd(&P.ps[curg * 128 + 2 * ln], ax);
        atomicAdd(&P.ps[curg * 128 + 2 * ln + 1], ay);
      }
    }
  }
  grid.sync();

  // ---------- P9: head (one graph per block) ----------
  {
    int g = b;
    int c = P.gstart[g + 1] - P.gstart[g];
    if (c < 1) c = 1;
    float inv = 1.f / (float)c;
    if (t < 128) hp[t] = P.ps[g * 128 + t] * inv;
    __syncthreads();
    if (t < 128) {
      float acc = P.l1b[t];
#pragma unroll 4
      for (int kk = 0; kk < 128; kk++) acc += hp[kk] * P.l1W[kk * 128 + t];
      hz[t] = acc;
    } else if (t < 192) {
      hz[t] = P.zax[g * 64 + (t - 128)];
    }
    __syncthreads();
    if (t < 8) {
      float acc = P.l2b[t];
#pragma unroll 4
      for (int kk = 0; kk < 192; kk++) acc += hz[kk] * P.l2W[kk * 8 + t];
      P.out[g * 8 + t] = acc;
    }
  }
}

extern "C" void kernel_launch(void* const* d_in, const int* in_sizes, int n_in,
                              void* d_out, int out_size, void* d_ws, size_t ws_size,
                              hipStream_t stream) {
  Params P;
  P.x   = (const float*)d_in[0];
  const int* ei = (const int*)d_in[1];
  P.bat = (const int*)d_in[2];
  P.axd = (const float*)d_in[3];
  P.W1  = (const float*)d_in[4];
  P.b1  = (const float*)d_in[5];
  P.W2  = (const float*)d_in[6];
  P.b2  = (const float*)d_in[7];
  P.l1W = (const float*)d_in[8];
  P.l1b = (const float*)d_in[9];
  P.axW = (const float*)d_in[10];
  P.axb = (const float*)d_in[11];
  P.l2W = (const float*)d_in[12];
  P.l2b = (const float*)d_in[13];
  P.out = (float*)d_out;

  int n = in_sizes[0] / 128;   // 50000
  int E = in_sizes[1] / 2;     // 640000
  int G = in_sizes[3] / 64;    // 512
  P.n = n; P.E = E; P.G = G;
  P.srcv = ei;
  P.dstv = ei + E;

  // workspace layout
  unsigned char* w = (unsigned char*)d_ws;
  P.h8      = w;                              w += (size_t)n * 128;       // fp8
  P.habuf   = (unsigned short*)w;             w += (size_t)n * 128 * 2;   // bf16
  P.wt1     = (unsigned short*)w;             w += 16384 * 2;
  P.wt2     = (unsigned short*)w;             w += 16384 * 2;
  P.csr     = (int*)w;                        w += (size_t)E * 4;
  P.offs    = (int*)w;                        w += (size_t)(n + 1) * 4;
  P.cursor8 = (int*)w;                        w += (size_t)8 * n * 4;
  P.cnt8    = (int*)w;                        w += (size_t)8 * n * 4;     // zeroed
  P.ps      = (float*)w;                      w += (size_t)G * 128 * 4;   // zeroed
  P.dinv    = (float*)w;                      w += (size_t)n * 4;
  P.partial = (int*)w;                        w += NBLK * 4;
  P.ppre    = (int*)w;                        w += NBLK * 4;
  P.gstart  = (int*)w;                        w += (size_t)(G + 1) * 4;
  P.zax     = (float*)w;                      w += (size_t)G * 64 * 4;

  // zero cnt8 + ps (adjacent) in one fill
  hipMemsetAsync(P.cnt8, 0, ((size_t)8 * n + (size_t)G * 128) * 4, stream);

  void* args[] = {&P};
  hipLaunchCooperativeKernel((void*)megakernel, dim3(NBLK), dim3(256), args, 0,
                             stream);
}

// Round 9
// 442.615 us; speedup vs baseline: 2.0108x; 2.0108x over previous
//
#include <hip/hip_runtime.h>
#include <hip/hip_cooperative_groups.h>

// patient_GCN: 2x GCNConv(128->128) + mean-pool + head.
// R9: R7 skeleton (separate kernels, high occupancy where it matters) +
//  - agg: one OCT (8 lanes) per node; fp8 row = 8 uint4; unroll-4 gathers,
//    no cross-lane reduction -> 8x fewer waves, ~4x per-lane MLP.
//  - fill || gemm1 fused in one kernel (interleaved block split).
//  - launches 12 -> 8 (deg+wprep+gbounds; coop scan; coop pool+head).
// R8 lesson: never let a 52KB-LDS phase share a launch with latency-bound
// phases; coop kernels here use tiny LDS at full occupancy.

namespace cg = cooperative_groups;

#define SNB 512   // scan blocks

typedef __attribute__((ext_vector_type(8))) short bf16x8;
typedef __attribute__((ext_vector_type(4))) float f32x4;
typedef __attribute__((ext_vector_type(2))) float f32x2;

static __device__ __forceinline__ unsigned short f2bf(float f) {
  unsigned u = __float_as_uint(f);
  return (unsigned short)((u + 0x7fffu + ((u >> 16) & 1u)) >> 16);
}
static __device__ __forceinline__ unsigned pack2(float a, float b) {
  return (unsigned)f2bf(a) | ((unsigned)f2bf(b) << 16);
}
static __device__ __forceinline__ unsigned char f2fp8(float v) {
  return (unsigned char)(__builtin_amdgcn_cvt_pk_fp8_f32(v, 0.f, 0, false) & 0xff);
}
static __device__ __forceinline__ void add16(float* a, uint4 h) {
  f32x2 t;
  t = __builtin_amdgcn_cvt_pk_f32_fp8(h.x, false); a[0] += t[0]; a[1] += t[1];
  t = __builtin_amdgcn_cvt_pk_f32_fp8(h.x, true);  a[2] += t[0]; a[3] += t[1];
  t = __builtin_amdgcn_cvt_pk_f32_fp8(h.y, false); a[4] += t[0]; a[5] += t[1];
  t = __builtin_amdgcn_cvt_pk_f32_fp8(h.y, true);  a[6] += t[0]; a[7] += t[1];
  t = __builtin_amdgcn_cvt_pk_f32_fp8(h.z, false); a[8] += t[0]; a[9] += t[1];
  t = __builtin_amdgcn_cvt_pk_f32_fp8(h.z, true);  a[10] += t[0]; a[11] += t[1];
  t = __builtin_amdgcn_cvt_pk_f32_fp8(h.w, false); a[12] += t[0]; a[13] += t[1];
  t = __builtin_amdgcn_cvt_pk_f32_fp8(h.w, true);  a[14] += t[0]; a[15] += t[1];
}

// ---- shared GEMM tile: H8[m0..m0+63,128](fp8) = dinv[m]*(X@W) ----
template <bool FP32IN>
static __device__ __forceinline__ void gemm_tile(const void* Xv, const uint4* WT4,
                                                 const float* dinv,
                                                 unsigned char* H8, int M, int m0,
                                                 unsigned short* sW,
                                                 unsigned short* sX, int tid) {
#pragma unroll
  for (int r = 0; r < 8; r++) {
    int idx = tid + r * 256;
    int nn = idx >> 4, c8 = idx & 15;
    *(uint4*)(sW + nn * 136 + c8 * 8) = WT4[idx];
  }
  if (FP32IN) {
    const float4* X4 = (const float4*)Xv;
#pragma unroll
    for (int r = 0; r < 8; r++) {
      int idx = tid + r * 256;
      int rr = idx >> 5, c4 = idx & 31;
      int m = m0 + rr;
      float4 v = make_float4(0.f, 0.f, 0.f, 0.f);
      if (m < M) v = X4[(size_t)m * 32 + c4];
      unsigned short* p = sX + rr * 136 + c4 * 4;
      *(ushort2*)(p) = make_ushort2(f2bf(v.x), f2bf(v.y));
      *(ushort2*)(p + 2) = make_ushort2(f2bf(v.z), f2bf(v.w));
    }
  } else {
    const uint4* X4 = (const uint4*)Xv;
#pragma unroll
    for (int r = 0; r < 4; r++) {
      int idx = tid + r * 256;
      int rr = idx >> 4, c8 = idx & 15;
      int m = m0 + rr;
      uint4 v = make_uint4(0u, 0u, 0u, 0u);
      if (m < M) v = X4[(size_t)m * 16 + c8];
      *(uint4*)(sX + rr * 136 + c8 * 8) = v;
    }
  }
  __syncthreads();
  int lane = tid & 63, wv = tid >> 6;
  int ln15 = lane & 15, q = lane >> 4;
  bf16x8 afrag[4];
#pragma unroll
  for (int c = 0; c < 4; c++)
    afrag[c] = *(const bf16x8*)(sX + (wv * 16 + ln15) * 136 + c * 32 + q * 8);
  int r0 = m0 + wv * 16 + q * 4;
  float dv[4];
#pragma unroll
  for (int rr = 0; rr < 4; rr++) dv[rr] = (r0 + rr < M) ? dinv[r0 + rr] : 0.f;
#pragma unroll
  for (int j = 0; j < 8; j++) {
    f32x4 acc = {0.f, 0.f, 0.f, 0.f};
#pragma unroll
    for (int c = 0; c < 4; c++) {
      bf16x8 bfrag = *(const bf16x8*)(sW + (j * 16 + ln15) * 136 + c * 32 + q * 8);
      acc = __builtin_amdgcn_mfma_f32_16x16x32_bf16(afrag[c], bfrag, acc, 0, 0, 0);
    }
    int col = j * 16 + ln15;
#pragma unroll
    for (int rr = 0; rr < 4; rr++) {
      int m = r0 + rr;
      if (m < M) H8[(size_t)m * 128 + col] = f2fp8(dv[rr] * acc[rr]);
    }
  }
}

// ---------------- deg (privatized) + wprep + gbounds ----------------
__global__ void k_deg_prep(const int* __restrict__ dstv, int* __restrict__ cnt8,
                           const float* __restrict__ W1, const float* __restrict__ W2,
                           unsigned short* __restrict__ wt1, unsigned short* __restrict__ wt2,
                           const int* __restrict__ bat, int* __restrict__ gstart,
                           int E, int n, int G, int EB) {
  int b = blockIdx.x, t = threadIdx.x;
  if (b < EB) {
    int e = b * 256 + t;
    int c = b & 7;
    if (e < E) atomicAdd(&cnt8[c * n + dstv[e]], 1);
  } else if (b < EB + 128) {
    int idx = (b - EB) * 256 + t;  // 32768
    int w = idx >> 14, r = (idx >> 7) & 127, kk = idx & 127;
    if (w == 0) wt1[r * 128 + kk] = f2bf(W1[kk * 128 + r]);
    else        wt2[r * 128 + kk] = f2bf(W2[kk * 128 + r]);
  } else {
    for (int g = t; g <= G; g += 256) {
      if (g == G) { gstart[g] = n; continue; }
      int lo = 0, hi = n;
      while (lo < hi) {
        int mid = (lo + hi) >> 1;
        if (bat[mid] < g) lo = mid + 1; else hi = mid;
      }
      gstart[g] = lo;
    }
  }
}

// ---------------- cooperative scan: offsets + cursors + dinv ----------------
__global__ __launch_bounds__(256) void k_scan(const int* __restrict__ cnt8,
                                              int* __restrict__ offs,
                                              int* __restrict__ cursor8,
                                              float* __restrict__ dinv,
                                              int* __restrict__ partial,
                                              int* __restrict__ ppre, int n) {
  cg::grid_group grid = cg::this_grid();
  __shared__ int s[256];
  int b = blockIdx.x, t = threadIdx.x;
  int CH = (n + SNB - 1) / SNB;  // 98
  int node = b * CH + t;
  bool valid = (t < CH) && (node < n);
  int vc[8];
  int tot = 0;
  if (valid) {
#pragma unroll
    for (int c = 0; c < 8; c++) { vc[c] = cnt8[c * n + node]; tot += vc[c]; }
  }
  s[t] = valid ? tot : 0;
  __syncthreads();
  for (int o = 1; o < 256; o <<= 1) {
    int v2 = (t >= o) ? s[t - o] : 0;
    __syncthreads();
    s[t] += v2;
    __syncthreads();
  }
  int pre = s[t] - (valid ? tot : 0);
  if (t == 0) partial[b] = s[255];
  grid.sync();
  if (b == 0) {
    int a0 = partial[2 * t], a1 = partial[2 * t + 1];
    s[t] = a0 + a1;
    __syncthreads();
    for (int o = 1; o < 256; o <<= 1) {
      int v2 = (t >= o) ? s[t - o] : 0;
      __syncthreads();
      s[t] += v2;
      __syncthreads();
    }
    int incl = s[t];
    ppre[2 * t] = incl - a0 - a1;
    ppre[2 * t + 1] = incl - a1;
    if (t == 255) offs[n] = incl;
  }
  grid.sync();
  if (valid) {
    int off = ppre[b] + pre;
    offs[node] = off;
    int run = off;
#pragma unroll
    for (int c = 0; c < 8; c++) { cursor8[c * n + node] = run; run += vc[c]; }
    dinv[node] = rsqrtf((float)(tot + 1));
  }
}

// ---------------- fill || gemm1 (interleaved block split) ----------------
__global__ __launch_bounds__(256, 2) void k_fill_gemm1(
    const int* __restrict__ srcv, const int* __restrict__ dstv,
    int* __restrict__ cursor8, int* __restrict__ csr,
    const float* __restrict__ x, const unsigned short* __restrict__ wt1,
    const float* __restrict__ dinv, unsigned char* __restrict__ h8,
    int E, int n, int NG) {
  __shared__ __align__(16) unsigned short sW[128 * 136];
  __shared__ __align__(16) unsigned short sX[64 * 136];
  int b = blockIdx.x, t = threadIdx.x;
  if (b < 2 * NG && (b & 1)) {
    gemm_tile<true>(x, (const uint4*)wt1, dinv, h8, n, (b >> 1) * 64, sW, sX, t);
  } else {
    int fi = (b < 2 * NG) ? (b >> 1) : (b - NG);
    int e = fi * 256 + t;
    if (e < E) {
      int c = fi & 7;  // == (e>>8)&7, same map as deg
      int p = atomicAdd(&cursor8[c * n + dstv[e]], 1);
      csr[p] = srcv[e];
    }
  }
}

// ---------------- gemm2 standalone ----------------
__global__ __launch_bounds__(256, 2) void k_gemm2(const unsigned short* __restrict__ X,
                                                  const unsigned short* __restrict__ wt2,
                                                  const float* __restrict__ dinv,
                                                  unsigned char* __restrict__ h8, int M) {
  __shared__ __align__(16) unsigned short sW[128 * 136];
  __shared__ __align__(16) unsigned short sX[64 * 136];
  gemm_tile<false>(X, (const uint4*)wt2, dinv, h8, M, blockIdx.x * 64, sW, sX,
                   threadIdx.x);
}

// ---------------- agg: one oct (8 lanes) per node ----------------
// out[i] = relu(b + dinv[i]*(Hs[i] + sum_{s in N(i)} Hs[s])), Hs fp8 rows.
__global__ __launch_bounds__(256) void k_agg(const uint4* __restrict__ Hs,
                                             const int* __restrict__ csr,
                                             const int* __restrict__ offs,
                                             const float* __restrict__ dinv,
                                             const float* __restrict__ bias,
                                             uint4* __restrict__ Ho, int n) {
  int t = threadIdx.x;
  int lane = t & 63, wv = t >> 6;
  int oct = lane >> 3, k = lane & 7;
  int i = blockIdx.x * 32 + wv * 8 + oct;
  bool valid = i < n;
  int ic = valid ? i : 0;
  int e0 = offs[ic];
  int e1 = valid ? offs[ic + 1] : e0;
  float acc[16];
#pragma unroll
  for (int r = 0; r < 16; r++) acc[r] = 0.f;
  uint4 hself = Hs[(size_t)ic * 8 + k];
  add16(acc, hself);
  int e = e0;
  for (; e + 4 <= e1; e += 4) {
    int s0 = csr[e], s1 = csr[e + 1], s2 = csr[e + 2], s3 = csr[e + 3];
    uint4 h0 = Hs[(size_t)s0 * 8 + k];
    uint4 h1 = Hs[(size_t)s1 * 8 + k];
    uint4 h2 = Hs[(size_t)s2 * 8 + k];
    uint4 h3 = Hs[(size_t)s3 * 8 + k];
    add16(acc, h0); add16(acc, h1); add16(acc, h2); add16(acc, h3);
  }
  for (; e < e1; e++) {
    uint4 h0 = Hs[(size_t)csr[e] * 8 + k];
    add16(acc, h0);
  }
  if (valid) {
    float di = dinv[i];
    const float4* B4 = (const float4*)bias;
    float o[16];
#pragma unroll
    for (int m4 = 0; m4 < 4; m4++) {
      float4 bb = B4[k * 4 + m4];
      o[m4 * 4 + 0] = fmaxf(bb.x + di * acc[m4 * 4 + 0], 0.f);
      o[m4 * 4 + 1] = fmaxf(bb.y + di * acc[m4 * 4 + 1], 0.f);
      o[m4 * 4 + 2] = fmaxf(bb.z + di * acc[m4 * 4 + 2], 0.f);
      o[m4 * 4 + 3] = fmaxf(bb.w + di * acc[m4 * 4 + 3], 0.f);
    }
    uint4 r0, r1;
    r0.x = pack2(o[0], o[1]);   r0.y = pack2(o[2], o[3]);
    r0.z = pack2(o[4], o[5]);   r0.w = pack2(o[6], o[7]);
    r1.x = pack2(o[8], o[9]);   r1.y = pack2(o[10], o[11]);
    r1.z = pack2(o[12], o[13]); r1.w = pack2(o[14], o[15]);
    Ho[(size_t)i * 16 + 2 * k] = r0;
    Ho[(size_t)i * 16 + 2 * k + 1] = r1;
  }
}

// ---------------- cooperative pool + head ----------------
__global__ __launch_bounds__(256) void k_poolhead(
    const unsigned* __restrict__ H2, const int* __restrict__ bat,
    float* __restrict__ ps, const int* __restrict__ gstart,
    const float* __restrict__ axd,
    const float* __restrict__ l1W, const float* __restrict__ l1b,
    const float* __restrict__ axW, const float* __restrict__ axb,
    const float* __restrict__ l2W, const float* __restrict__ l2b,
    float* __restrict__ out, int n, int G) {
  cg::grid_group grid = cg::this_grid();
  __shared__ float hp[128];
  __shared__ float ha[64];
  __shared__ float hz[192];
  int b = blockIdx.x, t = threadIdx.x;
  // phase A: pool (segmented atomic sum over 128-row chunk)
  {
    int r0v = b * 128;
    if (r0v < n) {
      int ln = t & 63, sub = t >> 6;
      int rend = r0v + 128; if (rend > n) rend = n;
      float ax = 0.f, ay = 0.f;
      int curg = -1;
      for (int r = r0v + sub; r < rend; r += 4) {
        int g = bat[r];
        if (g != curg) {
          if (curg >= 0) {
            atomicAdd(&ps[curg * 128 + 2 * ln], ax);
            atomicAdd(&ps[curg * 128 + 2 * ln + 1], ay);
          }
          curg = g; ax = 0.f; ay = 0.f;
        }
        unsigned h = H2[(size_t)r * 64 + ln];
        ax += __uint_as_float(h << 16);
        ay += __uint_as_float(h & 0xffff0000u);
      }
      if (curg >= 0) {
        atomicAdd(&ps[curg * 128 + 2 * ln], ax);
        atomicAdd(&ps[curg * 128 + 2 * ln + 1], ay);
      }
    }
  }
  grid.sync();
  // phase B: head, one graph per block
  {
    int g = b;
    if (g < G) {
      int c = gstart[g + 1] - gstart[g];
      if (c < 1) c = 1;
      float inv = 1.f / (float)c;
      if (t < 128) hp[t] = ps[g * 128 + t] * inv;
      else if (t < 192) ha[t - 128] = axd[g * 64 + (t - 128)];
      __syncthreads();
      if (t < 128) {
        float acc = l1b[t];
#pragma unroll 4
        for (int kk = 0; kk < 128; kk++) acc += hp[kk] * l1W[kk * 128 + t];
        hz[t] = acc;
      } else if (t < 192) {
        int j = t - 128;
        float acc = axb[j];
#pragma unroll 4
        for (int kk = 0; kk < 64; kk++) acc += ha[kk] * axW[kk * 64 + j];
        hz[128 + j] = acc;
      }
      __syncthreads();
      if (t < 8) {
        float acc = l2b[t];
#pragma unroll 4
        for (int kk = 0; kk < 192; kk++) acc += hz[kk] * l2W[kk * 8 + t];
        out[g * 8 + t] = acc;
      }
    }
  }
}

extern "C" void kernel_launch(void* const* d_in, const int* in_sizes, int n_in,
                              void* d_out, int out_size, void* d_ws, size_t ws_size,
                              hipStream_t stream) {
  const float* x   = (const float*)d_in[0];
  const int*   ei  = (const int*)d_in[1];
  const int*   bat = (const int*)d_in[2];
  const float* axd = (const float*)d_in[3];
  const float* W1  = (const float*)d_in[4];
  const float* b1  = (const float*)d_in[5];
  const float* W2  = (const float*)d_in[6];
  const float* b2  = (const float*)d_in[7];
  const float* l1W = (const float*)d_in[8];
  const float* l1b = (const float*)d_in[9];
  const float* axW = (const float*)d_in[10];
  const float* axb = (const float*)d_in[11];
  const float* l2W = (const float*)d_in[12];
  const float* l2b = (const float*)d_in[13];
  float* out = (float*)d_out;

  int n = in_sizes[0] / 128;   // 50000
  int E = in_sizes[1] / 2;     // 640000
  int G = in_sizes[3] / 64;    // 512

  unsigned char* w = (unsigned char*)d_ws;
  unsigned char*  h8    = w;                     w += (size_t)n * 128;
  unsigned short* habuf = (unsigned short*)w;    w += (size_t)n * 128 * 2;
  unsigned short* wt1   = (unsigned short*)w;    w += 16384 * 2;
  unsigned short* wt2   = (unsigned short*)w;    w += 16384 * 2;
  int*   csr     = (int*)w;                      w += (size_t)E * 4;
  int*   offs    = (int*)w;                      w += (size_t)(n + 1) * 4;
  int*   cursor8 = (int*)w;                      w += (size_t)8 * n * 4;
  int*   cnt8    = (int*)w;                      w += (size_t)8 * n * 4;   // zeroed
  float* ps      = (float*)w;                    w += (size_t)G * 128 * 4; // zeroed
  float* dinv    = (float*)w;                    w += (size_t)n * 4;
  int*   partial = (int*)w;                      w += SNB * 4;
  int*   ppre    = (int*)w;                      w += SNB * 4;
  int*   gstart  = (int*)w;                      w += (size_t)(G + 1) * 4;

  const int* srcv = ei;
  const int* dstv = ei + E;
  int EB = (E + 255) / 256;        // 2500
  int NG = (n + 63) / 64;          // 782

  hipMemsetAsync(cnt8, 0, ((size_t)8 * n + (size_t)G * 128) * 4, stream);
  k_deg_prep<<<EB + 129, 256, 0, stream>>>(dstv, cnt8, W1, W2, wt1, wt2, bat,
                                           gstart, E, n, G, EB);
  {
    void* args[] = {&cnt8, &offs, &cursor8, &dinv, &partial, &ppre, &n};
    hipLaunchCooperativeKernel((void*)k_scan, dim3(SNB), dim3(256), args, 0, stream);
  }
  k_fill_gemm1<<<NG + EB, 256, 0, stream>>>(srcv, dstv, cursor8, csr, x, wt1,
                                            dinv, h8, E, n, NG);
  k_agg<<<(n + 31) / 32, 256, 0, stream>>>((const uint4*)h8, csr, offs, dinv, b1,
                                           (uint4*)habuf, n);
  k_gemm2<<<NG, 256, 0, stream>>>(habuf, wt2, dinv, h8, n);
  k_agg<<<(n + 31) / 32, 256, 0, stream>>>((const uint4*)h8, csr, offs, dinv, b2,
                                           (uint4*)habuf, n);
  {
    void* args[] = {&habuf, &bat, &ps, &gstart, &axd, &l1W, &l1b, &axW, &axb,
                    &l2W, &l2b, &out, &n, &G};
    hipLaunchCooperativeKernel((void*)k_poolhead, dim3(G), dim3(256), args, 0,
                               stream);
  }
}

// Round 10
// 265.277 us; speedup vs baseline: 3.3550x; 1.6685x over previous
//
#include <hip/hip_runtime.h>

// patient_GCN: 2x GCNConv(128->128) + mean-pool + head.
// R10: NO cooperative launches (R9 lesson: grid.sync ~45us/sync on MI355X).
// R7 skeleton + R9's two wins: oct-per-node agg (8 lanes/node, fp8 rows,
// unroll-4, no cross-lane reduce) and fill||gemm1 in one regular kernel.

#define NPB 128  // nodes per pool block

typedef __attribute__((ext_vector_type(8))) short bf16x8;
typedef __attribute__((ext_vector_type(4))) float f32x4;
typedef __attribute__((ext_vector_type(2))) float f32x2;

static __device__ __forceinline__ unsigned short f2bf(float f) {
  unsigned u = __float_as_uint(f);
  return (unsigned short)((u + 0x7fffu + ((u >> 16) & 1u)) >> 16);
}
static __device__ __forceinline__ unsigned pack2(float a, float b) {
  return (unsigned)f2bf(a) | ((unsigned)f2bf(b) << 16);
}
static __device__ __forceinline__ unsigned char f2fp8(float v) {
  return (unsigned char)(__builtin_amdgcn_cvt_pk_fp8_f32(v, 0.f, 0, false) & 0xff);
}
static __device__ __forceinline__ void add16(float* a, uint4 h) {
  f32x2 t;
  t = __builtin_amdgcn_cvt_pk_f32_fp8(h.x, false); a[0] += t[0]; a[1] += t[1];
  t = __builtin_amdgcn_cvt_pk_f32_fp8(h.x, true);  a[2] += t[0]; a[3] += t[1];
  t = __builtin_amdgcn_cvt_pk_f32_fp8(h.y, false); a[4] += t[0]; a[5] += t[1];
  t = __builtin_amdgcn_cvt_pk_f32_fp8(h.y, true);  a[6] += t[0]; a[7] += t[1];
  t = __builtin_amdgcn_cvt_pk_f32_fp8(h.z, false); a[8] += t[0]; a[9] += t[1];
  t = __builtin_amdgcn_cvt_pk_f32_fp8(h.z, true);  a[10] += t[0]; a[11] += t[1];
  t = __builtin_amdgcn_cvt_pk_f32_fp8(h.w, false); a[12] += t[0]; a[13] += t[1];
  t = __builtin_amdgcn_cvt_pk_f32_fp8(h.w, true);  a[14] += t[0]; a[15] += t[1];
}

// ---- shared GEMM tile: H8[m0..m0+63,128](fp8) = dinv[m]*(X@W) ----
template <bool FP32IN>
static __device__ __forceinline__ void gemm_tile(const void* Xv, const uint4* WT4,
                                                 const float* dinv,
                                                 unsigned char* H8, int M, int m0,
                                                 unsigned short* sW,
                                                 unsigned short* sX, int tid) {
#pragma unroll
  for (int r = 0; r < 8; r++) {
    int idx = tid + r * 256;
    int nn = idx >> 4, c8 = idx & 15;
    *(uint4*)(sW + nn * 136 + c8 * 8) = WT4[idx];
  }
  if (FP32IN) {
    const float4* X4 = (const float4*)Xv;
#pragma unroll
    for (int r = 0; r < 8; r++) {
      int idx = tid + r * 256;
      int rr = idx >> 5, c4 = idx & 31;
      int m = m0 + rr;
      float4 v = make_float4(0.f, 0.f, 0.f, 0.f);
      if (m < M) v = X4[(size_t)m * 32 + c4];
      unsigned short* p = sX + rr * 136 + c4 * 4;
      *(ushort2*)(p) = make_ushort2(f2bf(v.x), f2bf(v.y));
      *(ushort2*)(p + 2) = make_ushort2(f2bf(v.z), f2bf(v.w));
    }
  } else {
    const uint4* X4 = (const uint4*)Xv;
#pragma unroll
    for (int r = 0; r < 4; r++) {
      int idx = tid + r * 256;
      int rr = idx >> 4, c8 = idx & 15;
      int m = m0 + rr;
      uint4 v = make_uint4(0u, 0u, 0u, 0u);
      if (m < M) v = X4[(size_t)m * 16 + c8];
      *(uint4*)(sX + rr * 136 + c8 * 8) = v;
    }
  }
  __syncthreads();
  int lane = tid & 63, wv = tid >> 6;
  int ln15 = lane & 15, q = lane >> 4;
  bf16x8 afrag[4];
#pragma unroll
  for (int c = 0; c < 4; c++)
    afrag[c] = *(const bf16x8*)(sX + (wv * 16 + ln15) * 136 + c * 32 + q * 8);
  int r0 = m0 + wv * 16 + q * 4;
  float dv[4];
#pragma unroll
  for (int rr = 0; rr < 4; rr++) dv[rr] = (r0 + rr < M) ? dinv[r0 + rr] : 0.f;
#pragma unroll
  for (int j = 0; j < 8; j++) {
    f32x4 acc = {0.f, 0.f, 0.f, 0.f};
#pragma unroll
    for (int c = 0; c < 4; c++) {
      bf16x8 bfrag = *(const bf16x8*)(sW + (j * 16 + ln15) * 136 + c * 32 + q * 8);
      acc = __builtin_amdgcn_mfma_f32_16x16x32_bf16(afrag[c], bfrag, acc, 0, 0, 0);
    }
    int col = j * 16 + ln15;
#pragma unroll
    for (int rr = 0; rr < 4; rr++) {
      int m = r0 + rr;
      if (m < M) H8[(size_t)m * 128 + col] = f2fp8(dv[rr] * acc[rr]);
    }
  }
}

// ---------------- deg (privatized) + wprep + gbounds ----------------
__global__ void k_deg_prep(const int* __restrict__ dstv, int* __restrict__ cnt8,
                           const float* __restrict__ W1, const float* __restrict__ W2,
                           unsigned short* __restrict__ wt1, unsigned short* __restrict__ wt2,
                           const int* __restrict__ bat, int* __restrict__ gstart,
                           int E, int n, int G, int EB) {
  int b = blockIdx.x, t = threadIdx.x;
  if (b < EB) {
    int e = b * 256 + t;
    int c = b & 7;
    if (e < E) atomicAdd(&cnt8[c * n + dstv[e]], 1);
  } else if (b < EB + 128) {
    int idx = (b - EB) * 256 + t;  // 32768
    int w = idx >> 14, r = (idx >> 7) & 127, kk = idx & 127;
    if (w == 0) wt1[r * 128 + kk] = f2bf(W1[kk * 128 + r]);
    else        wt2[r * 128 + kk] = f2bf(W2[kk * 128 + r]);
  } else {
    for (int g = t; g <= G; g += 256) {
      if (g == G) { gstart[g] = n; continue; }
      int lo = 0, hi = n;
      while (lo < hi) {
        int mid = (lo + hi) >> 1;
        if (bat[mid] < g) lo = mid + 1; else hi = mid;
      }
      gstart[g] = lo;
    }
  }
}

// ---------------- scan (3 small regular kernels, R7 style) ----------------
__global__ void k_part(const int* __restrict__ cnt8, int* __restrict__ part, int n) {
  __shared__ int s[256];
  int t = threadIdx.x;
  int idx = blockIdx.x * 256 + t;
  int v = 0;
  if (idx < n) {
#pragma unroll
    for (int c = 0; c < 8; c++) v += cnt8[c * n + idx];
  }
  s[t] = v;
  __syncthreads();
  for (int o = 128; o > 0; o >>= 1) {
    if (t < o) s[t] += s[t + o];
    __syncthreads();
  }
  if (t == 0) part[blockIdx.x] = s[0];
}

__global__ void k_scan1(const int* __restrict__ part, int* __restrict__ ppre,
                        int NB, int* __restrict__ offs, int n) {
  __shared__ int s[256];
  int t = threadIdx.x;
  int v = (t < NB) ? part[t] : 0;
  s[t] = v;
  __syncthreads();
  for (int o = 1; o < 256; o <<= 1) {
    int tmp = (t >= o) ? s[t - o] : 0;
    __syncthreads();
    s[t] += tmp;
    __syncthreads();
  }
  if (t < NB) ppre[t] = s[t] - v;
  if (t == NB - 1) offs[n] = s[t];
}

__global__ void k_offsets(const int* __restrict__ cnt8, const int* __restrict__ ppre,
                          int* __restrict__ offs, int* __restrict__ cursor8,
                          float* __restrict__ dinv, int n) {
  __shared__ int s[256];
  int t = threadIdx.x;
  int idx = blockIdx.x * 256 + t;
  int vc[8];
  int tot = 0;
  if (idx < n) {
#pragma unroll
    for (int c = 0; c < 8; c++) { vc[c] = cnt8[c * n + idx]; tot += vc[c]; }
  }
  s[t] = tot;
  __syncthreads();
  for (int o = 1; o < 256; o <<= 1) {
    int tmp = (t >= o) ? s[t - o] : 0;
    __syncthreads();
    s[t] += tmp;
    __syncthreads();
  }
  if (idx < n) {
    int off = ppre[blockIdx.x] + s[t] - tot;
    offs[idx] = off;
    int run = off;
#pragma unroll
    for (int c = 0; c < 8; c++) { cursor8[c * n + idx] = run; run += vc[c]; }
    dinv[idx] = rsqrtf((float)(tot + 1));
  }
}

// ---------------- fill || gemm1 (interleaved block split, regular kernel) ----
__global__ __launch_bounds__(256, 2) void k_fill_gemm1(
    const int* __restrict__ srcv, const int* __restrict__ dstv,
    int* __restrict__ cursor8, int* __restrict__ csr,
    const float* __restrict__ x, const unsigned short* __restrict__ wt1,
    const float* __restrict__ dinv, unsigned char* __restrict__ h8,
    int E, int n, int NG) {
  __shared__ __align__(16) unsigned short sW[128 * 136];
  __shared__ __align__(16) unsigned short sX[64 * 136];
  int b = blockIdx.x, t = threadIdx.x;
  if (b < 2 * NG && (b & 1)) {
    gemm_tile<true>(x, (const uint4*)wt1, dinv, h8, n, (b >> 1) * 64, sW, sX, t);
  } else {
    int fi = (b < 2 * NG) ? (b >> 1) : (b - NG);
    int e = fi * 256 + t;
    if (e < E) {
      int c = fi & 7;  // == (e>>8)&7, same map as deg
      int p = atomicAdd(&cursor8[c * n + dstv[e]], 1);
      csr[p] = srcv[e];
    }
  }
}

// ---------------- gemm2 standalone ----------------
__global__ __launch_bounds__(256, 2) void k_gemm2(const unsigned short* __restrict__ X,
                                                  const unsigned short* __restrict__ wt2,
                                                  const float* __restrict__ dinv,
                                                  unsigned char* __restrict__ h8, int M) {
  __shared__ __align__(16) unsigned short sW[128 * 136];
  __shared__ __align__(16) unsigned short sX[64 * 136];
  gemm_tile<false>(X, (const uint4*)wt2, dinv, h8, M, blockIdx.x * 64, sW, sX,
                   threadIdx.x);
}

// ---------------- agg: one oct (8 lanes) per node ----------------
// out[i] = relu(b + dinv[i]*(Hs[i] + sum_{s in N(i)} Hs[s])), Hs fp8 rows.
__global__ __launch_bounds__(256) void k_agg(const uint4* __restrict__ Hs,
                                             const int* __restrict__ csr,
                                             const int* __restrict__ offs,
                                             const float* __restrict__ dinv,
                                             const float* __restrict__ bias,
                                             uint4* __restrict__ Ho, int n) {
  int t = threadIdx.x;
  int lane = t & 63, wv = t >> 6;
  int oct = lane >> 3, k = lane & 7;
  int i = blockIdx.x * 32 + wv * 8 + oct;
  bool valid = i < n;
  int ic = valid ? i : 0;
  int e0 = offs[ic];
  int e1 = valid ? offs[ic + 1] : e0;
  float acc[16];
#pragma unroll
  for (int r = 0; r < 16; r++) acc[r] = 0.f;
  uint4 hself = Hs[(size_t)ic * 8 + k];
  add16(acc, hself);
  int e = e0;
  for (; e + 4 <= e1; e += 4) {
    int s0 = csr[e], s1 = csr[e + 1], s2 = csr[e + 2], s3 = csr[e + 3];
    uint4 h0 = Hs[(size_t)s0 * 8 + k];
    uint4 h1 = Hs[(size_t)s1 * 8 + k];
    uint4 h2 = Hs[(size_t)s2 * 8 + k];
    uint4 h3 = Hs[(size_t)s3 * 8 + k];
    add16(acc, h0); add16(acc, h1); add16(acc, h2); add16(acc, h3);
  }
  for (; e < e1; e++) {
    uint4 h0 = Hs[(size_t)csr[e] * 8 + k];
    add16(acc, h0);
  }
  if (valid) {
    float di = dinv[i];
    const float4* B4 = (const float4*)bias;
    float o[16];
#pragma unroll
    for (int m4 = 0; m4 < 4; m4++) {
      float4 bb = B4[k * 4 + m4];
      o[m4 * 4 + 0] = fmaxf(bb.x + di * acc[m4 * 4 + 0], 0.f);
      o[m4 * 4 + 1] = fmaxf(bb.y + di * acc[m4 * 4 + 1], 0.f);
      o[m4 * 4 + 2] = fmaxf(bb.z + di * acc[m4 * 4 + 2], 0.f);
      o[m4 * 4 + 3] = fmaxf(bb.w + di * acc[m4 * 4 + 3], 0.f);
    }
    uint4 r0, r1;
    r0.x = pack2(o[0], o[1]);   r0.y = pack2(o[2], o[3]);
    r0.z = pack2(o[4], o[5]);   r0.w = pack2(o[6], o[7]);
    r1.x = pack2(o[8], o[9]);   r1.y = pack2(o[10], o[11]);
    r1.z = pack2(o[12], o[13]); r1.w = pack2(o[14], o[15]);
    Ho[(size_t)i * 16 + 2 * k] = r0;
    Ho[(size_t)i * 16 + 2 * k + 1] = r1;
  }
}

// ---------------- pool: segmented atomic sum (bf16 in) ----------------
__global__ __launch_bounds__(256) void k_pool2(const unsigned* __restrict__ H2,
                                               const int* __restrict__ batch,
                                               float* __restrict__ ps, int n) {
  int t = threadIdx.x;
  int ln = t & 63, sub = t >> 6;
  int r0 = blockIdx.x * NPB + sub;
  int rend = min(blockIdx.x * NPB + NPB, n);
  float ax = 0.f, ay = 0.f;
  int curg = -1;
  for (int r = r0; r < rend; r += 4) {
    int g = batch[r];
    if (g != curg) {
      if (curg >= 0) {
        atomicAdd(&ps[curg * 128 + 2 * ln], ax);
        atomicAdd(&ps[curg * 128 + 2 * ln + 1], ay);
      }
      curg = g; ax = 0.f; ay = 0.f;
    }
    unsigned h = H2[(size_t)r * 64 + ln];
    ax += __uint_as_float(h << 16);
    ay += __uint_as_float(h & 0xffff0000u);
  }
  if (curg >= 0) {
    atomicAdd(&ps[curg * 128 + 2 * ln], ax);
    atomicAdd(&ps[curg * 128 + 2 * ln + 1], ay);
  }
}

// ---------------- head: 512 blocks x 192 threads ----------------
__global__ void k_head(const float* __restrict__ ps, const int* __restrict__ gstart,
                       const float* __restrict__ axd,
                       const float* __restrict__ l1W, const float* __restrict__ l1b,
                       const float* __restrict__ axW, const float* __restrict__ axb,
                       const float* __restrict__ l2W, const float* __restrict__ l2b,
                       float* __restrict__ out) {
  int g = blockIdx.x, t = threadIdx.x;
  __shared__ float p[128];
  __shared__ float a[64];
  __shared__ float z[192];
  int c = gstart[g + 1] - gstart[g];
  if (c < 1) c = 1;
  float inv = 1.f / (float)c;
  if (t < 128) p[t] = ps[g * 128 + t] * inv;
  else a[t - 128] = axd[g * 64 + (t - 128)];
  __syncthreads();
  if (t < 128) {
    float acc = l1b[t];
#pragma unroll 4
    for (int kk = 0; kk < 128; kk++) acc += p[kk] * l1W[kk * 128 + t];
    z[t] = acc;
  } else {
    int j = t - 128;
    float acc = axb[j];
#pragma unroll 4
    for (int kk = 0; kk < 64; kk++) acc += a[kk] * axW[kk * 64 + j];
    z[128 + j] = acc;
  }
  __syncthreads();
  if (t < 8) {
    float acc = l2b[t];
#pragma unroll 4
    for (int kk = 0; kk < 192; kk++) acc += z[kk] * l2W[kk * 8 + t];
    out[g * 8 + t] = acc;
  }
}

extern "C" void kernel_launch(void* const* d_in, const int* in_sizes, int n_in,
                              void* d_out, int out_size, void* d_ws, size_t ws_size,
                              hipStream_t stream) {
  const float* x   = (const float*)d_in[0];
  const int*   ei  = (const int*)d_in[1];
  const int*   bat = (const int*)d_in[2];
  const float* axd = (const float*)d_in[3];
  const float* W1  = (const float*)d_in[4];
  const float* b1  = (const float*)d_in[5];
  const float* W2  = (const float*)d_in[6];
  const float* b2  = (const float*)d_in[7];
  const float* l1W = (const float*)d_in[8];
  const float* l1b = (const float*)d_in[9];
  const float* axW = (const float*)d_in[10];
  const float* axb = (const float*)d_in[11];
  const float* l2W = (const float*)d_in[12];
  const float* l2b = (const float*)d_in[13];
  float* out = (float*)d_out;

  int n = in_sizes[0] / 128;   // 50000
  int E = in_sizes[1] / 2;     // 640000
  int G = in_sizes[3] / 64;    // 512

  unsigned char* w = (unsigned char*)d_ws;
  unsigned char*  h8    = w;                     w += (size_t)n * 128;
  unsigned short* habuf = (unsigned short*)w;    w += (size_t)n * 128 * 2;
  unsigned short* wt1   = (unsigned short*)w;    w += 16384 * 2;
  unsigned short* wt2   = (unsigned short*)w;    w += 16384 * 2;
  int*   csr     = (int*)w;                      w += (size_t)E * 4;
  int*   offs    = (int*)w;                      w += (size_t)(n + 1) * 4;
  int*   cursor8 = (int*)w;                      w += (size_t)8 * n * 4;
  int*   cnt8    = (int*)w;                      w += (size_t)8 * n * 4;   // zeroed
  float* ps      = (float*)w;                    w += (size_t)G * 128 * 4; // zeroed
  float* dinv    = (float*)w;                    w += (size_t)n * 4;
  int*   part    = (int*)w;                      w += 256 * 4;
  int*   ppre    = (int*)w;                      w += 256 * 4;
  int*   gstart  = (int*)w;                      w += (size_t)(G + 1) * 4;

  const int* srcv = ei;
  const int* dstv = ei + E;
  int EB = (E + 255) / 256;        // 2500
  int NG = (n + 63) / 64;          // 782
  int NB = (n + 255) / 256;        // 196

  hipMemsetAsync(cnt8, 0, ((size_t)8 * n + (size_t)G * 128) * 4, stream);
  k_deg_prep<<<EB + 129, 256, 0, stream>>>(dstv, cnt8, W1, W2, wt1, wt2, bat,
                                           gstart, E, n, G, EB);
  k_part<<<NB, 256, 0, stream>>>(cnt8, part, n);
  k_scan1<<<1, 256, 0, stream>>>(part, ppre, NB, offs, n);
  k_offsets<<<NB, 256, 0, stream>>>(cnt8, ppre, offs, cursor8, dinv, n);
  k_fill_gemm1<<<NG + EB, 256, 0, stream>>>(srcv, dstv, cursor8, csr, x, wt1,
                                            dinv, h8, E, n, NG);
  k_agg<<<(n + 31) / 32, 256, 0, stream>>>((const uint4*)h8, csr, offs, dinv, b1,
                                           (uint4*)habuf, n);
  k_gemm2<<<NG, 256, 0, stream>>>(habuf, wt2, dinv, h8, n);
  k_agg<<<(n + 31) / 32, 256, 0, stream>>>((const uint4*)h8, csr, offs, dinv, b2,
                                           (uint4*)habuf, n);
  k_pool2<<<(n + NPB - 1) / NPB, 256, 0, stream>>>((const unsigned*)habuf, bat, ps, n);
  k_head<<<G, 192, 0, stream>>>(ps, gstart, axd, l1W, l1b, axW, axb, l2W, l2b, out);
}

// Round 11
// 255.804 us; speedup vs baseline: 3.4792x; 1.0370x over previous
//
#include <hip/hip_runtime.h>

// patient_GCN: 2x GCNConv(128->128) + mean-pool + head.
// R11: direct ELL adjacency build (one atomic pass, cap 64, no scan/fill),
// fused with LDS-light gemm1 (sW only -> 4 blocks/CU, scatter at 16 waves/CU).
// gemm1 unscaled; agg1 applies dinv on the fly (fma16) and emits dinv[];
// gemm2 folds dinv; agg2 = cheap add16. 7 kernels + 1 memset.
// R9 lesson kept: no cooperative launches (grid.sync ~45us on MI355X).

#define NPB 128  // nodes per pool block
#define ELLCAP 64

typedef __attribute__((ext_vector_type(8))) short bf16x8;
typedef __attribute__((ext_vector_type(4))) float f32x4;
typedef __attribute__((ext_vector_type(2))) float f32x2;

static __device__ __forceinline__ unsigned short f2bf(float f) {
  unsigned u = __float_as_uint(f);
  return (unsigned short)((u + 0x7fffu + ((u >> 16) & 1u)) >> 16);
}
static __device__ __forceinline__ unsigned pack2(float a, float b) {
  return (unsigned)f2bf(a) | ((unsigned)f2bf(b) << 16);
}
static __device__ __forceinline__ unsigned char f2fp8(float v) {
  return (unsigned char)(__builtin_amdgcn_cvt_pk_fp8_f32(v, 0.f, 0, false) & 0xff);
}
static __device__ __forceinline__ void add16(float* a, uint4 h) {
  f32x2 t;
  t = __builtin_amdgcn_cvt_pk_f32_fp8(h.x, false); a[0] += t[0]; a[1] += t[1];
  t = __builtin_amdgcn_cvt_pk_f32_fp8(h.x, true);  a[2] += t[0]; a[3] += t[1];
  t = __builtin_amdgcn_cvt_pk_f32_fp8(h.y, false); a[4] += t[0]; a[5] += t[1];
  t = __builtin_amdgcn_cvt_pk_f32_fp8(h.y, true);  a[6] += t[0]; a[7] += t[1];
  t = __builtin_amdgcn_cvt_pk_f32_fp8(h.z, false); a[8] += t[0]; a[9] += t[1];
  t = __builtin_amdgcn_cvt_pk_f32_fp8(h.z, true);  a[10] += t[0]; a[11] += t[1];
  t = __builtin_amdgcn_cvt_pk_f32_fp8(h.w, false); a[12] += t[0]; a[13] += t[1];
  t = __builtin_amdgcn_cvt_pk_f32_fp8(h.w, true);  a[14] += t[0]; a[15] += t[1];
}
static __device__ __forceinline__ void fma16(float* a, float d, uint4 h) {
  f32x2 t;
  t = __builtin_amdgcn_cvt_pk_f32_fp8(h.x, false); a[0] = fmaf(d, t[0], a[0]); a[1] = fmaf(d, t[1], a[1]);
  t = __builtin_amdgcn_cvt_pk_f32_fp8(h.x, true);  a[2] = fmaf(d, t[0], a[2]); a[3] = fmaf(d, t[1], a[3]);
  t = __builtin_amdgcn_cvt_pk_f32_fp8(h.y, false); a[4] = fmaf(d, t[0], a[4]); a[5] = fmaf(d, t[1], a[5]);
  t = __builtin_amdgcn_cvt_pk_f32_fp8(h.y, true);  a[6] = fmaf(d, t[0], a[6]); a[7] = fmaf(d, t[1], a[7]);
  t = __builtin_amdgcn_cvt_pk_f32_fp8(h.z, false); a[8] = fmaf(d, t[0], a[8]); a[9] = fmaf(d, t[1], a[9]);
  t = __builtin_amdgcn_cvt_pk_f32_fp8(h.z, true);  a[10] = fmaf(d, t[0], a[10]); a[11] = fmaf(d, t[1], a[11]);
  t = __builtin_amdgcn_cvt_pk_f32_fp8(h.w, false); a[12] = fmaf(d, t[0], a[12]); a[13] = fmaf(d, t[1], a[13]);
  t = __builtin_amdgcn_cvt_pk_f32_fp8(h.w, true);  a[14] = fmaf(d, t[0], a[14]); a[15] = fmaf(d, t[1], a[15]);
}
static __device__ __forceinline__ void mul16(float* a, float d, uint4 h) {
  f32x2 t;
  t = __builtin_amdgcn_cvt_pk_f32_fp8(h.x, false); a[0] = d * t[0]; a[1] = d * t[1];
  t = __builtin_amdgcn_cvt_pk_f32_fp8(h.x, true);  a[2] = d * t[0]; a[3] = d * t[1];
  t = __builtin_amdgcn_cvt_pk_f32_fp8(h.y, false); a[4] = d * t[0]; a[5] = d * t[1];
  t = __builtin_amdgcn_cvt_pk_f32_fp8(h.y, true);  a[6] = d * t[0]; a[7] = d * t[1];
  t = __builtin_amdgcn_cvt_pk_f32_fp8(h.z, false); a[8] = d * t[0]; a[9] = d * t[1];
  t = __builtin_amdgcn_cvt_pk_f32_fp8(h.z, true);  a[10] = d * t[0]; a[11] = d * t[1];
  t = __builtin_amdgcn_cvt_pk_f32_fp8(h.w, false); a[12] = d * t[0]; a[13] = d * t[1];
  t = __builtin_amdgcn_cvt_pk_f32_fp8(h.w, true);  a[14] = d * t[0]; a[15] = d * t[1];
}

// ---------------- wprep (both W -> bf16 W^T) + gbounds ----------------
__global__ void k_wprep_gb(const float* __restrict__ W1, const float* __restrict__ W2,
                           unsigned short* __restrict__ wt1, unsigned short* __restrict__ wt2,
                           const int* __restrict__ bat, int* __restrict__ gstart,
                           int n, int G) {
  int b = blockIdx.x, t = threadIdx.x;
  if (b < 128) {
    int idx = b * 256 + t;  // 32768
    int w = idx >> 14, r = (idx >> 7) & 127, kk = idx & 127;
    if (w == 0) wt1[r * 128 + kk] = f2bf(W1[kk * 128 + r]);
    else        wt2[r * 128 + kk] = f2bf(W2[kk * 128 + r]);
  } else {
    for (int g = t; g <= G; g += 256) {
      if (g == G) { gstart[g] = n; continue; }
      int lo = 0, hi = n;
      while (lo < hi) {
        int mid = (lo + hi) >> 1;
        if (bat[mid] < g) lo = mid + 1; else hi = mid;
      }
      gstart[g] = lo;
    }
  }
}

// ---------------- mega1: gemm1 (LDS-light, unscaled) || ELL scatter ----------
// gemm blocks first (b < NG) so the MFMA pipeline starts immediately.
__global__ __launch_bounds__(256, 4) void k_mega1(
    const float* __restrict__ X, const uint4* __restrict__ WT4,
    unsigned char* __restrict__ H8,
    const int* __restrict__ srcv, const int* __restrict__ dstv,
    int* __restrict__ cnt, int* __restrict__ ell,
    int E, int M, int NG) {
  __shared__ __align__(16) unsigned short sW[128 * 136];
  int b = blockIdx.x, t = threadIdx.x;
  if (b < NG) {
    // ---- gemm tile, A-frags from global, no sX ----
#pragma unroll
    for (int r = 0; r < 8; r++) {
      int idx = t + r * 256;
      int nn = idx >> 4, c8 = idx & 15;
      *(uint4*)(sW + nn * 136 + c8 * 8) = WT4[idx];
    }
    __syncthreads();
    int lane = t & 63, wv = t >> 6;
    int ln15 = lane & 15, q = lane >> 4;
    int m0 = b * 64;
    int ma = m0 + wv * 16 + ln15;          // A-row this lane supplies
    int mc = ma < M ? ma : 0;
    const float4* X4 = (const float4*)X;
    bf16x8 afrag[4];
#pragma unroll
    for (int c = 0; c < 4; c++) {
      float4 va = X4[(size_t)mc * 32 + c * 8 + q * 2];
      float4 vb = X4[(size_t)mc * 32 + c * 8 + q * 2 + 1];
      bf16x8 f;
      f[0] = (short)f2bf(va.x); f[1] = (short)f2bf(va.y);
      f[2] = (short)f2bf(va.z); f[3] = (short)f2bf(va.w);
      f[4] = (short)f2bf(vb.x); f[5] = (short)f2bf(vb.y);
      f[6] = (short)f2bf(vb.z); f[7] = (short)f2bf(vb.w);
      afrag[c] = f;
    }
    int r0 = m0 + wv * 16 + q * 4;
#pragma unroll
    for (int j = 0; j < 8; j++) {
      f32x4 acc = {0.f, 0.f, 0.f, 0.f};
#pragma unroll
      for (int c = 0; c < 4; c++) {
        bf16x8 bfrag = *(const bf16x8*)(sW + (j * 16 + ln15) * 136 + c * 32 + q * 8);
        acc = __builtin_amdgcn_mfma_f32_16x16x32_bf16(afrag[c], bfrag, acc, 0, 0, 0);
      }
      int col = j * 16 + ln15;
#pragma unroll
      for (int rr = 0; rr < 4; rr++) {
        int m = r0 + rr;
        if (m < M) H8[(size_t)m * 128 + col] = f2fp8(acc[rr]);
      }
    }
  } else {
    // ---- ELL scatter: one atomic pass builds adjacency ----
    int e = (b - NG) * 256 + t;
    if (e < E) {
      int d = dstv[e];
      int slot = atomicAdd(&cnt[d], 1);
      if (slot < ELLCAP) ell[(size_t)d * ELLCAP + slot] = srcv[e];
    }
  }
}

// ---------------- agg1: oct/node, on-the-fly dinv (fma16), emits dinv[] ------
// out[i] = relu(b1 + di*(di*Hu[i] + sum_s ds*Hu[s]))
__global__ __launch_bounds__(256) void k_agg1(const uint4* __restrict__ Hu,
                                              const int* __restrict__ ell,
                                              const int* __restrict__ cnt,
                                              const float* __restrict__ bias,
                                              uint4* __restrict__ Ho,
                                              float* __restrict__ dinv, int n) {
  int t = threadIdx.x;
  int oct = t >> 3, k = t & 7;
  int i = blockIdx.x * 32 + oct;
  bool valid = i < n;
  int ic = valid ? i : 0;
  int raw = cnt[ic];
  float di = rsqrtf((float)(raw + 1));
  int deg = raw < ELLCAP ? raw : ELLCAP;
  float acc[16];
  uint4 hs = Hu[(size_t)ic * 8 + k];
  mul16(acc, di, hs);  // self term (pre outer-di)
  const int* row = ell + (size_t)ic * ELLCAP;
  int j = 0;
  for (; j + 4 <= deg; j += 4) {
    int s0 = row[j], s1 = row[j + 1], s2 = row[j + 2], s3 = row[j + 3];
    float d0 = rsqrtf((float)(cnt[s0] + 1));
    float d1 = rsqrtf((float)(cnt[s1] + 1));
    float d2 = rsqrtf((float)(cnt[s2] + 1));
    float d3 = rsqrtf((float)(cnt[s3] + 1));
    uint4 h0 = Hu[(size_t)s0 * 8 + k];
    uint4 h1 = Hu[(size_t)s1 * 8 + k];
    uint4 h2 = Hu[(size_t)s2 * 8 + k];
    uint4 h3 = Hu[(size_t)s3 * 8 + k];
    fma16(acc, d0, h0); fma16(acc, d1, h1); fma16(acc, d2, h2); fma16(acc, d3, h3);
  }
  for (; j < deg; j++) {
    int s0 = row[j];
    float d0 = rsqrtf((float)(cnt[s0] + 1));
    uint4 h0 = Hu[(size_t)s0 * 8 + k];
    fma16(acc, d0, h0);
  }
  if (valid) {
    const float4* B4 = (const float4*)bias;
    float o[16];
#pragma unroll
    for (int m4 = 0; m4 < 4; m4++) {
      float4 bb = B4[k * 4 + m4];
      o[m4 * 4 + 0] = fmaxf(bb.x + di * acc[m4 * 4 + 0], 0.f);
      o[m4 * 4 + 1] = fmaxf(bb.y + di * acc[m4 * 4 + 1], 0.f);
      o[m4 * 4 + 2] = fmaxf(bb.z + di * acc[m4 * 4 + 2], 0.f);
      o[m4 * 4 + 3] = fmaxf(bb.w + di * acc[m4 * 4 + 3], 0.f);
    }
    uint4 r0, r1;
    r0.x = pack2(o[0], o[1]);   r0.y = pack2(o[2], o[3]);
    r0.z = pack2(o[4], o[5]);   r0.w = pack2(o[6], o[7]);
    r1.x = pack2(o[8], o[9]);   r1.y = pack2(o[10], o[11]);
    r1.z = pack2(o[12], o[13]); r1.w = pack2(o[14], o[15]);
    Ho[(size_t)i * 16 + 2 * k] = r0;
    Ho[(size_t)i * 16 + 2 * k + 1] = r1;
    if (k == 0) dinv[i] = di;
  }
}

// ---------------- gemm2: full tile (sW+sX), dinv folded -> prescaled fp8 ------
__global__ __launch_bounds__(256, 2) void k_gemm2(const unsigned short* __restrict__ Xb,
                                                  const uint4* __restrict__ WT4,
                                                  const float* __restrict__ dinv,
                                                  unsigned char* __restrict__ H8, int M) {
  __shared__ __align__(16) unsigned short sW[128 * 136];
  __shared__ __align__(16) unsigned short sX[64 * 136];
  int tid = threadIdx.x;
  int m0 = blockIdx.x * 64;
#pragma unroll
  for (int r = 0; r < 8; r++) {
    int idx = tid + r * 256;
    int nn = idx >> 4, c8 = idx & 15;
    *(uint4*)(sW + nn * 136 + c8 * 8) = WT4[idx];
  }
  const uint4* X4 = (const uint4*)Xb;
#pragma unroll
  for (int r = 0; r < 4; r++) {
    int idx = tid + r * 256;
    int rr = idx >> 4, c8 = idx & 15;
    int m = m0 + rr;
    uint4 v = make_uint4(0u, 0u, 0u, 0u);
    if (m < M) v = X4[(size_t)m * 16 + c8];
    *(uint4*)(sX + rr * 136 + c8 * 8) = v;
  }
  __syncthreads();
  int lane = tid & 63, wv = tid >> 6;
  int ln15 = lane & 15, q = lane >> 4;
  bf16x8 afrag[4];
#pragma unroll
  for (int c = 0; c < 4; c++)
    afrag[c] = *(const bf16x8*)(sX + (wv * 16 + ln15) * 136 + c * 32 + q * 8);
  int r0 = m0 + wv * 16 + q * 4;
  float dv[4];
#pragma unroll
  for (int rr = 0; rr < 4; rr++) dv[rr] = (r0 + rr < M) ? dinv[r0 + rr] : 0.f;
#pragma unroll
  for (int j = 0; j < 8; j++) {
    f32x4 acc = {0.f, 0.f, 0.f, 0.f};
#pragma unroll
    for (int c = 0; c < 4; c++) {
      bf16x8 bfrag = *(const bf16x8*)(sW + (j * 16 + ln15) * 136 + c * 32 + q * 8);
      acc = __builtin_amdgcn_mfma_f32_16x16x32_bf16(afrag[c], bfrag, acc, 0, 0, 0);
    }
    int col = j * 16 + ln15;
#pragma unroll
    for (int rr = 0; rr < 4; rr++) {
      int m = r0 + rr;
      if (m < M) H8[(size_t)m * 128 + col] = f2fp8(dv[rr] * acc[rr]);
    }
  }
}

// ---------------- agg2: oct/node, prescaled rows (add16) ----------------
// out[i] = relu(b2 + di*(Hs[i] + sum_s Hs[s]))
__global__ __launch_bounds__(256) void k_agg2(const uint4* __restrict__ Hs,
                                              const int* __restrict__ ell,
                                              const int* __restrict__ cnt,
                                              const float* __restrict__ dinv,
                                              const float* __restrict__ bias,
                                              uint4* __restrict__ Ho, int n) {
  int t = threadIdx.x;
  int oct = t >> 3, k = t & 7;
  int i = blockIdx.x * 32 + oct;
  bool valid = i < n;
  int ic = valid ? i : 0;
  int raw = cnt[ic];
  int deg = raw < ELLCAP ? raw : ELLCAP;
  float acc[16];
#pragma unroll
  for (int r = 0; r < 16; r++) acc[r] = 0.f;
  uint4 hs = Hs[(size_t)ic * 8 + k];
  add16(acc, hs);
  const int* row = ell + (size_t)ic * ELLCAP;
  int j = 0;
  for (; j + 4 <= deg; j += 4) {
    int s0 = row[j], s1 = row[j + 1], s2 = row[j + 2], s3 = row[j + 3];
    uint4 h0 = Hs[(size_t)s0 * 8 + k];
    uint4 h1 = Hs[(size_t)s1 * 8 + k];
    uint4 h2 = Hs[(size_t)s2 * 8 + k];
    uint4 h3 = Hs[(size_t)s3 * 8 + k];
    add16(acc, h0); add16(acc, h1); add16(acc, h2); add16(acc, h3);
  }
  for (; j < deg; j++) {
    uint4 h0 = Hs[(size_t)row[j] * 8 + k];
    add16(acc, h0);
  }
  if (valid) {
    float di = dinv[i];
    const float4* B4 = (const float4*)bias;
    float o[16];
#pragma unroll
    for (int m4 = 0; m4 < 4; m4++) {
      float4 bb = B4[k * 4 + m4];
      o[m4 * 4 + 0] = fmaxf(bb.x + di * acc[m4 * 4 + 0], 0.f);
      o[m4 * 4 + 1] = fmaxf(bb.y + di * acc[m4 * 4 + 1], 0.f);
      o[m4 * 4 + 2] = fmaxf(bb.z + di * acc[m4 * 4 + 2], 0.f);
      o[m4 * 4 + 3] = fmaxf(bb.w + di * acc[m4 * 4 + 3], 0.f);
    }
    uint4 r0, r1;
    r0.x = pack2(o[0], o[1]);   r0.y = pack2(o[2], o[3]);
    r0.z = pack2(o[4], o[5]);   r0.w = pack2(o[6], o[7]);
    r1.x = pack2(o[8], o[9]);   r1.y = pack2(o[10], o[11]);
    r1.z = pack2(o[12], o[13]); r1.w = pack2(o[14], o[15]);
    Ho[(size_t)i * 16 + 2 * k] = r0;
    Ho[(size_t)i * 16 + 2 * k + 1] = r1;
  }
}

// ---------------- pool: segmented atomic sum (bf16 in) ----------------
__global__ __launch_bounds__(256) void k_pool2(const unsigned* __restrict__ H2,
                                               const int* __restrict__ batch,
                                               float* __restrict__ ps, int n) {
  int t = threadIdx.x;
  int ln = t & 63, sub = t >> 6;
  int r0 = blockIdx.x * NPB + sub;
  int rend = min(blockIdx.x * NPB + NPB, n);
  float ax = 0.f, ay = 0.f;
  int curg = -1;
  for (int r = r0; r < rend; r += 4) {
    int g = batch[r];
    if (g != curg) {
      if (curg >= 0) {
        atomicAdd(&ps[curg * 128 + 2 * ln], ax);
        atomicAdd(&ps[curg * 128 + 2 * ln + 1], ay);
      }
      curg = g; ax = 0.f; ay = 0.f;
    }
    unsigned h = H2[(size_t)r * 64 + ln];
    ax += __uint_as_float(h << 16);
    ay += __uint_as_float(h & 0xffff0000u);
  }
  if (curg >= 0) {
    atomicAdd(&ps[curg * 128 + 2 * ln], ax);
    atomicAdd(&ps[curg * 128 + 2 * ln + 1], ay);
  }
}

// ---------------- head: 512 blocks x 192 threads ----------------
__global__ void k_head(const float* __restrict__ ps, const int* __restrict__ gstart,
                       const float* __restrict__ axd,
                       const float* __restrict__ l1W, const float* __restrict__ l1b,
                       const float* __restrict__ axW, const float* __restrict__ axb,
                       const float* __restrict__ l2W, const float* __restrict__ l2b,
                       float* __restrict__ out) {
  int g = blockIdx.x, t = threadIdx.x;
  __shared__ float p[128];
  __shared__ float a[64];
  __shared__ float z[192];
  int c = gstart[g + 1] - gstart[g];
  if (c < 1) c = 1;
  float inv = 1.f / (float)c;
  if (t < 128) p[t] = ps[g * 128 + t] * inv;
  else a[t - 128] = axd[g * 64 + (t - 128)];
  __syncthreads();
  if (t < 128) {
    float acc = l1b[t];
#pragma unroll 4
    for (int kk = 0; kk < 128; kk++) acc += p[kk] * l1W[kk * 128 + t];
    z[t] = acc;
  } else {
    int j = t - 128;
    float acc = axb[j];
#pragma unroll 4
    for (int kk = 0; kk < 64; kk++) acc += a[kk] * axW[kk * 64 + j];
    z[128 + j] = acc;
  }
  __syncthreads();
  if (t < 8) {
    float acc = l2b[t];
#pragma unroll 4
    for (int kk = 0; kk < 192; kk++) acc += z[kk] * l2W[kk * 8 + t];
    out[g * 8 + t] = acc;
  }
}

extern "C" void kernel_launch(void* const* d_in, const int* in_sizes, int n_in,
                              void* d_out, int out_size, void* d_ws, size_t ws_size,
                              hipStream_t stream) {
  const float* x   = (const float*)d_in[0];
  const int*   ei  = (const int*)d_in[1];
  const int*   bat = (const int*)d_in[2];
  const float* axd = (const float*)d_in[3];
  const float* W1  = (const float*)d_in[4];
  const float* b1  = (const float*)d_in[5];
  const float* W2  = (const float*)d_in[6];
  const float* b2  = (const float*)d_in[7];
  const float* l1W = (const float*)d_in[8];
  const float* l1b = (const float*)d_in[9];
  const float* axW = (const float*)d_in[10];
  const float* axb = (const float*)d_in[11];
  const float* l2W = (const float*)d_in[12];
  const float* l2b = (const float*)d_in[13];
  float* out = (float*)d_out;

  int n = in_sizes[0] / 128;   // 50000
  int E = in_sizes[1] / 2;     // 640000
  int G = in_sizes[3] / 64;    // 512

  unsigned char* w = (unsigned char*)d_ws;
  unsigned char*  h8    = w;                     w += (size_t)n * 128;       // fp8
  unsigned short* habuf = (unsigned short*)w;    w += (size_t)n * 128 * 2;   // bf16
  unsigned short* wt1   = (unsigned short*)w;    w += 16384 * 2;
  unsigned short* wt2   = (unsigned short*)w;    w += 16384 * 2;
  int*   ell    = (int*)w;                       w += (size_t)n * ELLCAP * 4;
  int*   cnt    = (int*)w;                       w += (size_t)n * 4;         // zeroed
  float* ps     = (float*)w;                     w += (size_t)G * 128 * 4;   // zeroed
  float* dinv   = (float*)w;                     w += (size_t)n * 4;
  int*   gstart = (int*)w;                       w += (size_t)(G + 1) * 4;

  const int* srcv = ei;
  const int* dstv = ei + E;
  int EB = (E + 255) / 256;   // 2500
  int NG = (n + 63) / 64;     // 782

  hipMemsetAsync(cnt, 0, ((size_t)n + (size_t)G * 128) * 4, stream);
  k_wprep_gb<<<129, 256, 0, stream>>>(W1, W2, wt1, wt2, bat, gstart, n, G);
  k_mega1<<<NG + EB, 256, 0, stream>>>(x, (const uint4*)wt1, h8, srcv, dstv,
                                       cnt, ell, E, n, NG);
  k_agg1<<<(n + 31) / 32, 256, 0, stream>>>((const uint4*)h8, ell, cnt, b1,
                                            (uint4*)habuf, dinv, n);
  k_gemm2<<<NG, 256, 0, stream>>>(habuf, (const uint4*)wt2, dinv, h8, n);
  k_agg2<<<(n + 31) / 32, 256, 0, stream>>>((const uint4*)h8, ell, cnt, dinv, b2,
                                            (uint4*)habuf, n);
  k_pool2<<<(n + NPB - 1) / NPB, 256, 0, stream>>>((const unsigned*)habuf, bat, ps, n);
  k_head<<<G, 192, 0, stream>>>(ps, gstart, axd, l1W, l1b, axW, axb, l2W, l2b, out);
}